// Round 3
// baseline (16.060 us; speedup 1.0000x reference)
//
#include <hip/hip_runtime.h>
#include <math.h>

// QueueMemory: compat() <= 0 always (0.5 - hard_sigmoid(norm>=0)), EPS=0.51 > 0,
// so cond_q/cond_s are provably False. Reduces to:
//   r      = argmin(index)                    (first occurrence)
//   m      = argmax(index over j != r)        (first occurrence)  [= global argmax
//            unless index is constant, since argmin-first == argmax-first only then]
//   reward = sum_t states_seq[0, t, F-1]
//   out = reward > index[m] ? (states_seq[0,T-1,:], reward) : (memory[0,m,:], index[m])
//
// Single kernel, last-block-ticket finalize. All cross-block traffic goes through
// device-scope atomics on d_ws (atomicExch to publish, atomicAdd(x,0) to read), so
// per-XCD L2 non-coherence cannot serve stale partials. The ticket counter is
// zeroed by an 8-byte hipMemsetAsync node each call (d_ws is poisoned 0xAA once and
// never re-poisoned; the finalizing block varies per run but the reduction it
// performs is deterministic, so the output is run-invariant).

namespace {
constexpr int kT      = 128;
constexpr int kF      = 512;
constexpr int kMemLen = 65536;
constexpr int kBlocks = 64;
constexpr int kThr    = 256;   // 64 blk * 256 thr * 4 elems = 65536
// d_ws layout as unsigned long long[]:
//   [0]      ticket counter (uint at byte 0) — memset to 0 each call
//   [2+i]    block i min pair  {hi: idx, lo: float bits}
//   [66+i]   block i max pair
//   [130]    reward float bits (uint)
constexpr int kMinBase = 2;
constexpr int kMaxBase = 66;
constexpr int kRewardSlot = 130;
}

__device__ inline unsigned long long pack_pair(float v, int i) {
    return ((unsigned long long)(unsigned int)i << 32) |
           (unsigned long long)__float_as_uint(v);
}
__device__ inline void unpack_pair(unsigned long long p, float& v, int& i) {
    v = __uint_as_float((unsigned int)p);
    i = (int)(unsigned int)(p >> 32);
}
__device__ inline void combine_min(float& v, int& i, float ov, int oi) {
    if (ov < v || (ov == v && oi < i)) { v = ov; i = oi; }
}
__device__ inline void combine_max(float& v, int& i, float ov, int oi) {
    if (ov > v || (ov == v && oi < i)) { v = ov; i = oi; }
}

__global__ __launch_bounds__(kThr)
void qm_fused(const float* __restrict__ states_seq,  // (1, 128, 512)
              const float* __restrict__ memory,      // (1, 65536, 512)
              const float* __restrict__ index,       // (1, 65536, 1)
              unsigned long long* __restrict__ ws,
              float* __restrict__ out) {              // 513 floats
    struct MinMax { float mnv; int mni; float mxv; int mxi; };
    __shared__ MinMax s_w[kThr / 64];
    __shared__ float  s_rpart[2];
    __shared__ int    s_last;
    __shared__ int    s_m;
    __shared__ float  s_maxv;
    __shared__ float  s_reward;

    const int tid = threadIdx.x;
    const int bid = blockIdx.x;

    // Block 0 additionally computes the reward column sum; issue those loads first
    // so they overlap the index loads.
    float rv = 0.0f;
    if (bid == 0 && tid < kT) rv = states_seq[tid * kF + (kF - 1)];

    // ---- per-block min/max over a 1024-element slice of index ----
    const int gid = bid * kThr + tid;
    float4 v = reinterpret_cast<const float4*>(index)[gid];
    const int b = 4 * gid;
    float mnv = v.x; int mni = b;
    float mxv = v.x; int mxi = b;
    if (v.y < mnv) { mnv = v.y; mni = b + 1; }
    if (v.y > mxv) { mxv = v.y; mxi = b + 1; }
    if (v.z < mnv) { mnv = v.z; mni = b + 2; }
    if (v.z > mxv) { mxv = v.z; mxi = b + 2; }
    if (v.w < mnv) { mnv = v.w; mni = b + 3; }
    if (v.w > mxv) { mxv = v.w; mxi = b + 3; }

    #pragma unroll
    for (int s = 1; s < 64; s <<= 1) {
        float onv = __shfl_xor(mnv, s);
        int   oni = __shfl_xor(mni, s);
        float oxv = __shfl_xor(mxv, s);
        int   oxi = __shfl_xor(mxi, s);
        combine_min(mnv, mni, onv, oni);
        combine_max(mxv, mxi, oxv, oxi);
    }
    if ((tid & 63) == 0) s_w[tid >> 6] = {mnv, mni, mxv, mxi};

    if (bid == 0 && tid < kT) {
        #pragma unroll
        for (int s = 1; s < 64; s <<= 1) rv += __shfl_xor(rv, s);
        if ((tid & 63) == 0) s_rpart[tid >> 6] = rv;
    }
    __syncthreads();

    // ---- publish partials (device-scope atomics), take ticket ----
    if (tid == 0) {
        MinMax a = s_w[0];
        #pragma unroll
        for (int i = 1; i < kThr / 64; ++i) {
            combine_min(a.mnv, a.mni, s_w[i].mnv, s_w[i].mni);
            combine_max(a.mxv, a.mxi, s_w[i].mxv, s_w[i].mxi);
        }
        atomicExch(&ws[kMinBase + bid], pack_pair(a.mnv, a.mni));
        atomicExch(&ws[kMaxBase + bid], pack_pair(a.mxv, a.mxi));
        if (bid == 0) {
            float reward = s_rpart[0] + s_rpart[1];
            atomicExch((unsigned int*)&ws[kRewardSlot], __float_as_uint(reward));
        }
        __threadfence();  // drain exchanges before the ticket
        unsigned int old = atomicAdd((unsigned int*)&ws[0], 1u);
        s_last = (old == (unsigned int)(kBlocks - 1));
    }
    __syncthreads();
    if (!s_last) return;

    // ---- finalize (exactly one block reaches here, after all 64 published) ----
    __threadfence();
    if (tid < kBlocks) {
        unsigned long long pmin = atomicAdd(&ws[kMinBase + tid], 0ull);
        unsigned long long pmax = atomicAdd(&ws[kMaxBase + tid], 0ull);
        float bmnv, bmxv; int bmni, bmxi;
        unpack_pair(pmin, bmnv, bmni);
        unpack_pair(pmax, bmxv, bmxi);
        #pragma unroll
        for (int s = 1; s < 64; s <<= 1) {
            float onv = __shfl_xor(bmnv, s);
            int   oni = __shfl_xor(bmni, s);
            float oxv = __shfl_xor(bmxv, s);
            int   oxi = __shfl_xor(bmxi, s);
            combine_min(bmnv, bmni, onv, oni);
            combine_max(bmxv, bmxi, oxv, oxi);
        }
        if (tid == 0) {
            int m = bmxi;
            if (bmxi == bmni) m = (bmni == 0) ? 1 : 0;  // constant-array edge case
            s_m      = m;
            s_maxv   = bmxv;
            s_reward = __uint_as_float(
                atomicAdd((unsigned int*)&ws[kRewardSlot], 0u));
        }
    }
    __syncthreads();

    const float reward = s_reward;
    const float maxv   = s_maxv;
    const float* src;
    float idxval;
    if (reward > maxv) {
        // appended element wins only on strict > (earlier positions win ties)
        src    = states_seq + (size_t)(kT - 1) * kF;
        idxval = reward;
    } else {
        src    = memory + (size_t)s_m * kF;
        idxval = maxv;  // == index[m]
    }
    const float4* src4 = reinterpret_cast<const float4*>(src);
    float4*       out4 = reinterpret_cast<float4*>(out);
    if (tid < kF / 4) out4[tid] = src4[tid];
    if (tid == 0) out[kF] = idxval;
}

extern "C" void kernel_launch(void* const* d_in, const int* in_sizes, int n_in,
                              void* d_out, int out_size, void* d_ws, size_t ws_size,
                              hipStream_t stream) {
    const float* states_seq = (const float*)d_in[0];
    // d_in[1] = maximum_route: provably unused (cond_s always False).
    const float* memory = (const float*)d_in[2];
    const float* index  = (const float*)d_in[3];
    float* out = (float*)d_out;
    unsigned long long* ws = (unsigned long long*)d_ws;

    hipMemsetAsync(d_ws, 0, 8, stream);  // zero the ticket counter
    qm_fused<<<kBlocks, kThr, 0, stream>>>(states_seq, memory, index, ws, out);
}